// Round 22
// baseline (158.969 us; speedup 1.0000x reference)
//
#include <hip/hip_runtime.h>

// RegionProposalNetwork post-processing for MI355X — full-device pipeline.
//  K1 hist     : 288 balanced slices -> PRIVATE per-slice 12-bit histograms
//  K2 thresh   : per (image,level) sum slice histograms -> threshold bin T (+ flag);
//                writes summed hist (exact fallback) and zeroes gcnt
//  K3 collect  : 288 slices -> compact u >= T into per-level global key lists
//  K4 sortgather: per (image,level) RANK-BY-COUNT selection of collected keys
//                (keys unique -> rank = #{greater} gives the exact descending
//                order == lax.top_k order) + fused gather/decode/clip/sigmoid/
//                validity + per-level max (fallback: exact radix refine)
//  K5 sortprep : STABLE PARTITION (== the bitonic; proof in r21)
//  K6 maskbuild: one 64x64 IoU tile per wave; LDS column staging; diag/offdiag split;
//                division-free IoU decision (exact division fallback in-band)
//  K7 scan     : heavy-rows-only staging (rowany-gated) + r9-verified windowed walk
//  K8 final    : rank-merge of 5 sorted kept lists per image
// NOTE: gkeys/phist/sghist are overlaid on maskg (all consumed before maskbuild writes).

#define A_TOTAL 261888
#define B_IMG   16
#define K_TOT   4768
#define NEGV    -1e9f
#define BBOX_CLIP 4.135166556742356f  // log(1000/16)
#define ROWS    1024
#define JOBS_PER_IMG 622              // 4*136 + 78
#define TOTAL_JOBS   9952             // 16*622
#define CAPG    4096
#define SL_PER_IMG 18

__constant__ int c_lvl_off[5] = {0, 196608, 245760, 258048, 261120};
__constant__ int c_lvl_n[5]   = {196608, 49152, 12288, 3072, 768};
__constant__ int c_lvl_k[5]   = {1000, 1000, 1000, 1000, 768};
__constant__ int c_sel_off[5] = {0, 1000, 2000, 3000, 4000};
__constant__ int c_lvl_sst[5] = {0, 12, 15, 16, 17};   // slice start within image
__constant__ int c_lvl_scn[5] = {12, 3, 1, 1, 1};      // slice count

__constant__ int c_s_lvl[SL_PER_IMG]   = {0,0,0,0,0,0,0,0,0,0,0,0, 1,1,1, 2, 3, 4};
__constant__ int c_s_base4[SL_PER_IMG] = {0,4096,8192,12288,16384,20480,24576,28672,
                                          32768,36864,40960,45056, 0,4096,8192, 0, 0, 0};
__constant__ int c_s_len4[SL_PER_IMG]  = {4096,4096,4096,4096,4096,4096,4096,4096,
                                          4096,4096,4096,4096, 4096,4096,4096, 3072, 768, 192};

typedef unsigned long long ull;

__device__ __forceinline__ unsigned fkey(float f) {
    unsigned u = __float_as_uint(f);
    return (u & 0x80000000u) ? ~u : (u | 0x80000000u);
}
__device__ __forceinline__ float inv_fkey(unsigned h) {
    return (h & 0x80000000u) ? __uint_as_float(h ^ 0x80000000u)
                             : __uint_as_float(~h);
}
__device__ __forceinline__ ull rlane_u64(ull v, int l) {
    int lo = __builtin_amdgcn_readlane((int)(unsigned)v, l);
    int hi = __builtin_amdgcn_readlane((int)(unsigned)(v >> 32), l);
    return ((ull)(unsigned)hi << 32) | (unsigned)lo;
}

// IoU decision: fdiv_rn(inter,den) > 0.7f, resolved without division outside a
// conservative band (rel 1e-6 >> all rounding effects); in-band lanes use the
// EXACT original division -> decision bit identical for every pair.
__device__ __forceinline__ bool iou_gt(float inter, float den) {
    float thr  = __fmul_rn(0.7f, den);
    float band = __fmul_rn(thr, 1.0e-6f);
    if (inter > __fadd_rn(thr, band)) return true;
    if (inter < __fsub_rn(thr, band)) return false;
    return (inter / den) > 0.7f;
}

// ------------------------------------------- K1: private per-slice histogram
__global__ void __launch_bounds__(256)
hist_kernel(const float* __restrict__ obj, unsigned* __restrict__ phist) {
    const int blk = blockIdx.x, b = blk / SL_PER_IMG, r = blk % SL_PER_IMG;
    const int lvl = c_s_lvl[r], base4 = c_s_base4[r], len4 = c_s_len4[r];
    const int tid = threadIdx.x;
    const float4* src4 = (const float4*)(obj + (size_t)b * A_TOTAL + c_lvl_off[lvl]) + base4;

    __shared__ unsigned lh[2 * 4096];
    for (int i = tid; i < 2 * 4096; i += 256) lh[i] = 0u;
    __syncthreads();
    unsigned* myh = lh + (tid & 1) * 4096;
    for (int i = tid; i < len4; i += 256) {
        float4 v = src4[i];
        atomicAdd(&myh[fkey(v.x) >> 20], 1u);
        atomicAdd(&myh[fkey(v.y) >> 20], 1u);
        atomicAdd(&myh[fkey(v.z) >> 20], 1u);
        atomicAdd(&myh[fkey(v.w) >> 20], 1u);
    }
    __syncthreads();
    for (int bin = tid; bin < 4096; bin += 256)
        phist[(size_t)blk * 4096 + bin] = lh[bin] + lh[4096 + bin];
}

// --------------------- K2: sum slices -> threshold (+ summed hist, gcnt zero)
__global__ void __launch_bounds__(1024)
thresh_kernel(const unsigned* __restrict__ phist, unsigned* __restrict__ sghist,
              unsigned* __restrict__ Tg, int* __restrict__ flagg,
              int* __restrict__ gcnt) {
    const int g = blockIdx.x, b = g / 5, lvl = g % 5;
    const int n = c_lvl_n[lvl], k = c_lvl_k[lvl];
    const int tid = threadIdx.x;
    if (tid == 0) gcnt[g] = 0;
    if (k >= n) {
        if (tid == 0) { Tg[g] = 0u; flagg[g] = 0; }
        return;
    }
    const int sst = b * SL_PER_IMG + c_lvl_sst[lvl], scn = c_lvl_scn[lvl];
    __shared__ unsigned csum[1024];
    __shared__ int sh_chunk;
    __shared__ unsigned hist4[4096];
    unsigned s = 0;
    for (int q = 0; q < 4; ++q) {
        const int bin = tid * 4 + q;
        unsigned v = 0;
        for (int s2 = 0; s2 < scn; ++s2)
            v += phist[(size_t)(sst + s2) * 4096 + bin];
        hist4[bin] = v;
        sghist[g * 4096 + bin] = v;     // exact summed hist for the fallback path
        s += v;
    }
    csum[tid] = s;
    __syncthreads();
    for (int o = 1; o < 1024; o <<= 1) {
        unsigned v = (tid + o < 1024) ? csum[tid + o] : 0u;
        __syncthreads();
        csum[tid] += v;
        __syncthreads();
    }
    if (csum[tid] >= (unsigned)k && (tid == 1023 || csum[tid + 1] < (unsigned)k))
        sh_chunk = tid;
    __syncthreads();
    if (tid == 0) {
        int I = sh_chunk;
        unsigned cum = (I < 1023) ? csum[I + 1] : 0u;
        unsigned bin = 0, cntge = 0;
        for (int c = I * 4 + 3; c >= I * 4; --c) {
            unsigned h = hist4[c];
            if (cum + h >= (unsigned)k) { bin = (unsigned)c; cntge = cum + h; break; }
            cum += h;
        }
        if (cntge <= CAPG) { Tg[g] = bin << 20; flagg[g] = 0; }
        else               { Tg[g] = 0u;        flagg[g] = 1; }
    }
}

// ------------------------------------------------------------ K3: collect
__global__ void __launch_bounds__(256)
collect_kernel(const float* __restrict__ obj, const unsigned* __restrict__ Tg,
               const int* __restrict__ flagg, ull* __restrict__ gkeys,
               int* __restrict__ gcnt) {
    const int blk = blockIdx.x, b = blk / SL_PER_IMG, r = blk % SL_PER_IMG;
    const int lvl = c_s_lvl[r], base4 = c_s_base4[r], len4 = c_s_len4[r];
    const int g = b * 5 + lvl;
    const int tid = threadIdx.x;
    if (flagg[g]) return;
    const unsigned T = Tg[g];
    const float4* src4 = (const float4*)(obj + (size_t)b * A_TOTAL + c_lvl_off[lvl]) + base4;

    __shared__ ull buf[CAPG];
    __shared__ int scnt, sbase;
    if (tid == 0) scnt = 0;
    __syncthreads();
    for (int i = tid; i < len4; i += 256) {
        float4 v = src4[i];
        unsigned u0 = fkey(v.x), u1 = fkey(v.y), u2 = fkey(v.z), u3 = fkey(v.w);
        int al = (base4 + i) << 2;
        if (u0 >= T) { int p = atomicAdd(&scnt, 1); if (p < CAPG) buf[p] = ((ull)u0 << 32) | (unsigned)(~(unsigned)(al + 0)); }
        if (u1 >= T) { int p = atomicAdd(&scnt, 1); if (p < CAPG) buf[p] = ((ull)u1 << 32) | (unsigned)(~(unsigned)(al + 1)); }
        if (u2 >= T) { int p = atomicAdd(&scnt, 1); if (p < CAPG) buf[p] = ((ull)u2 << 32) | (unsigned)(~(unsigned)(al + 2)); }
        if (u3 >= T) { int p = atomicAdd(&scnt, 1); if (p < CAPG) buf[p] = ((ull)u3 << 32) | (unsigned)(~(unsigned)(al + 3)); }
    }
    __syncthreads();
    int c2 = scnt < CAPG ? scnt : CAPG;
    if (tid == 0) sbase = atomicAdd(&gcnt[g], c2);
    __syncthreads();
    for (int j = tid; j < c2; j += 256) {
        int d = sbase + j;
        if (d < CAPG) gkeys[g * CAPG + d] = buf[j];
    }
}

// ------------------- K4: rank-by-count selection + fused gather
__global__ void __launch_bounds__(1024)
sortgather_kernel(const float* __restrict__ obj, const float* __restrict__ deltas,
                  const float* __restrict__ anchors, const int* __restrict__ ihp,
                  const int* __restrict__ iwp, const unsigned* __restrict__ sghist,
                  const unsigned* __restrict__ Tg, const int* __restrict__ flagg,
                  const ull* __restrict__ gkeys, const int* __restrict__ gcnt,
                  float4* __restrict__ cand_box, float* __restrict__ cand_masked,
                  float* __restrict__ mclvl) {
    const int g = blockIdx.x, b = g / 5, lvl = g % 5;
    const int n = c_lvl_n[lvl], k = c_lvl_k[lvl], off = c_lvl_off[lvl];
    const int so = c_sel_off[lvl];
    const int tid = threadIdx.x;

    __shared__ ull cl[CAPG];
    __shared__ ull srt[1024];
    __shared__ float redf[1024];
    __shared__ unsigned fhist[256];
    __shared__ unsigned csum[1024];
    __shared__ int sh_chunk, sh_rem, sh_cnt;
    __shared__ unsigned sh_bin;

    int cnt;
    if (!flagg[g]) {
        cnt = gcnt[g];
        if (cnt < 0) cnt = 0;
        if (cnt > CAPG) cnt = CAPG;
        for (int i = tid; i < cnt; i += 1024) cl[i] = gkeys[g * CAPG + i];
    } else {
        // ---- pathological-tie fallback: single-block radix refine (reads src) ----
        const float4* src4 = (const float4*)(obj + (size_t)b * A_TOTAL + off);
        const int n4 = n >> 2;
        unsigned s = 0;
        for (int q = 0; q < 4; ++q) s += sghist[g * 4096 + tid * 4 + q];
        csum[tid] = s;
        __syncthreads();
        for (int o = 1; o < 1024; o <<= 1) {
            unsigned v = (tid + o < 1024) ? csum[tid + o] : 0u;
            __syncthreads();
            csum[tid] += v;
            __syncthreads();
        }
        if (csum[tid] >= (unsigned)k && (tid == 1023 || csum[tid + 1] < (unsigned)k))
            sh_chunk = tid;
        __syncthreads();
        if (tid == 0) {
            int I = sh_chunk;
            unsigned cum = (I < 1023) ? csum[I + 1] : 0u;
            for (int c = I * 4 + 3; c >= I * 4; --c) {
                unsigned h = sghist[g * 4096 + c];
                if (cum + h >= (unsigned)k) { sh_bin = (unsigned)c; sh_rem = k - (int)cum; break; }
                cum += h;
            }
        }
        __syncthreads();
        unsigned prefix = sh_bin;
        int rem = sh_rem, done = 12;
        while (done < 32) {
            int w = (32 - done >= 8) ? 8 : (32 - done);
            int shift = 32 - done - w;
            int nb = 1 << w;
            for (int i = tid; i < nb; i += 1024) fhist[i] = 0u;
            __syncthreads();
            for (int i = tid; i < n4; i += 1024) {
                float4 v = src4[i];
                unsigned uu0 = fkey(v.x), uu1 = fkey(v.y), uu2 = fkey(v.z), uu3 = fkey(v.w);
                if ((uu0 >> (shift + w)) == prefix) atomicAdd(&fhist[(uu0 >> shift) & (nb - 1)], 1u);
                if ((uu1 >> (shift + w)) == prefix) atomicAdd(&fhist[(uu1 >> shift) & (nb - 1)], 1u);
                if ((uu2 >> (shift + w)) == prefix) atomicAdd(&fhist[(uu2 >> shift) & (nb - 1)], 1u);
                if ((uu3 >> (shift + w)) == prefix) atomicAdd(&fhist[(uu3 >> shift) & (nb - 1)], 1u);
            }
            __syncthreads();
            if (tid == 0) {
                unsigned cum = 0;
                for (int c = nb - 1; c >= 0; --c) {
                    unsigned h = fhist[c];
                    if (cum + h >= (unsigned)rem) {
                        sh_bin = (prefix << w) | (unsigned)c;
                        sh_rem = rem - (int)cum;
                        break;
                    }
                    cum += h;
                }
            }
            __syncthreads();
            prefix = sh_bin; rem = sh_rem; done += w;
            __syncthreads();
        }
        unsigned T = prefix;
        if (tid == 0) sh_cnt = 0;
        __syncthreads();
        for (int i = tid; i < n4; i += 1024) {
            float4 v = src4[i];
            unsigned u0 = fkey(v.x), u1 = fkey(v.y), u2 = fkey(v.z), u3 = fkey(v.w);
            int base = i << 2;
            if (u0 >= T) { int p = atomicAdd(&sh_cnt, 1); if (p < CAPG) cl[p] = ((ull)u0 << 32) | (unsigned)(~(unsigned)(base + 0)); }
            if (u1 >= T) { int p = atomicAdd(&sh_cnt, 1); if (p < CAPG) cl[p] = ((ull)u1 << 32) | (unsigned)(~(unsigned)(base + 1)); }
            if (u2 >= T) { int p = atomicAdd(&sh_cnt, 1); if (p < CAPG) cl[p] = ((ull)u2 << 32) | (unsigned)(~(unsigned)(base + 2)); }
            if (u3 >= T) { int p = atomicAdd(&sh_cnt, 1); if (p < CAPG) cl[p] = ((ull)u3 << 32) | (unsigned)(~(unsigned)(base + 3)); }
        }
        __syncthreads();
        cnt = sh_cnt; if (cnt > CAPG) cnt = CAPG;
    }
    __syncthreads();

    // ---- rank-by-count: keys unique -> rank = #{j : cl[j] > x} is the exact
    // descending-order position (== what the bitonic produced). cnt >= k always.
    for (int e = tid; e < cnt; e += 1024) {
        ull x = cl[e];
        int rank = 0;
        #pragma unroll 4
        for (int j = 0; j < cnt; ++j)
            rank += (cl[j] > x) ? 1 : 0;
        if (rank < k) srt[rank] = x;
    }
    __syncthreads();

    // ---- fused gather/decode (rank tid, key in srt[tid]) ----
    const float imh = (float)ihp[0];
    const float imw = (float)iwp[0];
    float mx = 0.0f;
    if (tid < k) {
        ull kv = srt[tid];
        unsigned idx = (unsigned)off + (unsigned)(~(unsigned)kv);
        float logit = inv_fkey((unsigned)(kv >> 32));
        float4 anc = ((const float4*)anchors)[idx];
        float w = __fsub_rn(anc.z, anc.x);
        float h = __fsub_rn(anc.w, anc.y);
        float cx = __fadd_rn(anc.x, __fmul_rn(0.5f, w));
        float cy = __fadd_rn(anc.y, __fmul_rn(0.5f, h));
        float4 dl = ((const float4*)deltas)[(size_t)b * A_TOTAL + idx];
        float dx = dl.x, dy = dl.y;
        float dw = fminf(dl.z, BBOX_CLIP);
        float dh = fminf(dl.w, BBOX_CLIP);
        float pcx = __fadd_rn(__fmul_rn(dx, w), cx);
        float pcy = __fadd_rn(__fmul_rn(dy, h), cy);
        float pw = __fmul_rn(expf(dw), w);
        float ph = __fmul_rn(expf(dh), h);
        float x1 = __fsub_rn(pcx, __fmul_rn(0.5f, pw));
        float y1 = __fsub_rn(pcy, __fmul_rn(0.5f, ph));
        float x2 = __fadd_rn(pcx, __fmul_rn(0.5f, pw));
        float y2 = __fadd_rn(pcy, __fmul_rn(0.5f, ph));
        x1 = fminf(fmaxf(x1, 0.0f), imw);
        y1 = fminf(fmaxf(y1, 0.0f), imh);
        x2 = fminf(fmaxf(x2, 0.0f), imw);
        y2 = fminf(fmaxf(y2, 0.0f), imh);
        float score = 1.0f / __fadd_rn(1.0f, expf(-logit));
        bool valid = (__fsub_rn(x2, x1) >= 0.001f) && (__fsub_rn(y2, y1) >= 0.001f);
        cand_box[b * K_TOT + so + tid] = make_float4(x1, y1, x2, y2);
        cand_masked[b * K_TOT + so + tid] = valid ? score : NEGV;
        mx = fmaxf(fmaxf(x1, y1), fmaxf(x2, y2));
    }
    redf[tid] = mx;
    __syncthreads();
    for (int s2 = 512; s2 > 0; s2 >>= 1) {
        if (tid < s2) redf[tid] = fmaxf(redf[tid], redf[tid + s2]);
        __syncthreads();
    }
    if (tid == 0) mclvl[g] = redf[0];
}

// ------ K5: stable valid/invalid partition (== r7 bitonic; proof in r21)
__global__ void __launch_bounds__(1024)
sortprep_kernel(const float4* __restrict__ cand_box, const float* __restrict__ cand_masked,
                const float* __restrict__ mclvl,
                float4* __restrict__ sbox, float* __restrict__ sar,
                ull* __restrict__ skeys, ull* __restrict__ svalid,
                ull* __restrict__ growany) {
    const int g = blockIdx.x, b = g / 5, lvl = g % 5;
    const int n = c_lvl_k[lvl], so = c_sel_off[lvl];
    const int tid = threadIdx.x;
    const int wid = tid >> 6, lane = tid & 63;
    __shared__ int wsum[16];
    __shared__ int wbase[17];

    const bool inrange = tid < n;
    float m = 0.0f;
    bool valid = false;
    if (inrange) {
        m = cand_masked[b * K_TOT + so + tid];
        valid = (m > -1e8f);
    }
    ull bal  = __ballot(valid);                  // valid => inrange
    ull ibal = __ballot(inrange && !valid);
    ull ltmask = lane ? (~0ull >> (64 - lane)) : 0ull;
    int lpre  = __popcll(bal & ltmask);
    int lprei = __popcll(ibal & ltmask);
    if (lane == 0) wsum[wid] = __popcll(bal);
    __syncthreads();
    if (tid == 0) {
        int s = 0;
        for (int w = 0; w < 16; ++w) { wbase[w] = s; s += wsum[w]; }
        wbase[16] = s;
    }
    __syncthreads();
    const int nv = wbase[16];

    float mc = fmaxf(fmaxf(fmaxf(mclvl[b * 5 + 0], mclvl[b * 5 + 1]),
                           fmaxf(mclvl[b * 5 + 2], mclvl[b * 5 + 3])),
                     mclvl[b * 5 + 4]);
    const float offs = __fmul_rn((float)lvl, __fadd_rn(mc, 1.0f));

    if (inrange) {
        int r;
        if (valid) r = wbase[wid] + lpre;
        else       r = nv + (wid * 64 - wbase[wid]) + lprei;
        skeys[g * ROWS + r] = ((ull)fkey(m) << 32) | (unsigned)(~(unsigned)(so + tid));
        float4 bb = cand_box[b * K_TOT + so + tid];
        float X1 = __fadd_rn(bb.x, offs);
        float Y1 = __fadd_rn(bb.y, offs);
        float X2 = __fadd_rn(bb.z, offs);
        float Y2 = __fadd_rn(bb.w, offs);
        sbox[g * ROWS + r] = make_float4(X1, Y1, X2, Y2);
        sar[g * ROWS + r] = __fmul_rn(fmaxf(__fsub_rn(X2, X1), 0.0f),
                                      fmaxf(__fsub_rn(Y2, Y1), 0.0f));
    } else {
        skeys[g * ROWS + tid] = 0ull;
        sbox[g * ROWS + tid] = make_float4(0.f, 0.f, 0.f, 0.f);
        sar[g * ROWS + tid] = 0.f;
    }
    if (tid < 16) {
        int lo = nv - tid * 64; lo = lo < 0 ? 0 : (lo > 64 ? 64 : lo);
        int hi = n - tid * 64;  hi = hi < 0 ? 0 : (hi > 64 ? 64 : hi);
        ull wlo = (lo >= 64) ? ~0ull : ((1ull << lo) - 1ull);
        ull whi = (hi >= 64) ? ~0ull : ((1ull << hi) - 1ull);
        svalid[g * 16 + tid] = whi & ~wlo;
        growany[g * 16 + tid] = 0ull;
    }
}

// -------- K6: mask build (1 tile/wave), LDS column staging, diag split,
//          division-free IoU decision (exact fallback in-band)
__global__ void __launch_bounds__(256)
maskbuild_kernel(const float4* __restrict__ sbox, const float* __restrict__ sar,
                 ull* __restrict__ maskg, ull* __restrict__ growany) {
    const int wave = (blockIdx.x * 256 + threadIdx.x) >> 6;
    const int lane = threadIdx.x & 63;
    const int wv = threadIdx.x >> 6;
    __shared__ float4 scb[256];
    __shared__ float sca2[256];
    const int img = wave / JOBS_PER_IMG;
    int rem = wave - img * JOBS_PER_IMG;
    int lvl, t;
    if (rem >= 544) { lvl = 4; t = rem - 544; }
    else            { lvl = rem / 136; t = rem - lvl * 136; }
    const int g = img * 5 + lvl;
    const int Rp = (c_lvl_k[lvl] + 63) >> 6;  // 16 or 12
    int rt = 0, tt = t;
    while (tt >= Rp - rt) { tt -= Rp - rt; ++rt; }
    const int ct = rt + tt;
    const int r0 = rt << 6, c0 = ct << 6;

    const float4 rb = sbox[g * ROWS + r0 + lane];
    const float  ra = sar[g * ROWS + r0 + lane];
    scb[threadIdx.x]  = sbox[g * ROWS + c0 + lane];
    sca2[threadIdx.x] = sar[g * ROWS + c0 + lane];
    __syncthreads();
    const int row = r0 + lane;

    ull m = 0ull;
    if (rt == ct) {
        for (int jj = 0; jj < 64; ++jj) {
            float4 cbj = scb[(wv << 6) | jj];
            float aj   = sca2[(wv << 6) | jj];
            float xx1 = fmaxf(rb.x, cbj.x);
            float yy1 = fmaxf(rb.y, cbj.y);
            float xx2 = fminf(rb.z, cbj.z);
            float yy2 = fminf(rb.w, cbj.w);
            float inter = __fmul_rn(fmaxf(__fsub_rn(xx2, xx1), 0.0f),
                                    fmaxf(__fsub_rn(yy2, yy1), 0.0f));
            float den = __fadd_rn(__fsub_rn(__fadd_rn(ra, aj), inter), 1e-9f);
            bool s = iou_gt(inter, den) && (c0 + jj > row);
            m |= ((ull)s) << jj;
        }
    } else {
        // off-diagonal: c0 >= r0+64 > row, condition always true (bit-identical)
        for (int jj = 0; jj < 64; ++jj) {
            float4 cbj = scb[(wv << 6) | jj];
            float aj   = sca2[(wv << 6) | jj];
            float xx1 = fmaxf(rb.x, cbj.x);
            float yy1 = fmaxf(rb.y, cbj.y);
            float xx2 = fminf(rb.z, cbj.z);
            float yy2 = fminf(rb.w, cbj.w);
            float inter = __fmul_rn(fmaxf(__fsub_rn(xx2, xx1), 0.0f),
                                    fmaxf(__fsub_rn(yy2, yy1), 0.0f));
            float den = __fadd_rn(__fsub_rn(__fadd_rn(ra, aj), inter), 1e-9f);
            bool s = iou_gt(inter, den);
            m |= ((ull)s) << jj;
        }
    }
    maskg[(size_t)(g * 16 + ct) * ROWS + row] = m;
    // publish per-row "mask nonempty" (converged wave, one atomic per tile)
    ull ab = __ballot(m != 0ull);
    if (lane == 0 && ab)
        atomicOr(&growany[g * 16 + rt], ab);
}

// ----- K7: heavy-rows-only staging + r9-verified windowed greedy walk
__global__ void __launch_bounds__(1024)
scan_kernel(const ull* __restrict__ maskg, const ull* __restrict__ growany,
            const ull* __restrict__ svalid, const ull* __restrict__ skeys,
            ull* __restrict__ klist, int* __restrict__ kcount) {
    const int g = blockIdx.x, lvl = g % 5;
    const int n = c_lvl_k[lvl];          // 1000 or 768
    const int Rp = (n + 63) >> 6;        // 16 or 12
    const int tid = threadIdx.x;

    __shared__ ull lmask[1024 * 17];     // row-major, stride 17; only heavy rows staged
    __shared__ ull lsk[1024];            // sorted keys staged to LDS

    // ---- phase 1: stage ONLY heavy rows (rowany-gated) + all keys
    if (tid < n) {
        ull rw = growany[g * 16 + (tid >> 6)];
        if ((rw >> (tid & 63)) & 1ull) {
            #pragma unroll 16
            for (int w = 0; w < 16; ++w) {
                ull v = (w < Rp) ? maskg[(size_t)(g * 16 + w) * ROWS + tid] : 0ull;
                lmask[tid * 17 + w] = v;
            }
        }
        lsk[tid] = skeys[g * ROWS + tid];
    }
    __syncthreads();
    if (tid >= 16) return;

    // ---- phase 2: r9-VERIFIED windowed serial walk (16 lanes hold remv words)
    const int lane = tid;
    ull remv_l = svalid[g * 16 + lane];
    ull rany_l = growany[g * 16 + lane];
    ull kpv = 0ull;
    for (int W = 0; W < Rp; ++W) {
        const int base = W << 6;
        const int lim = (n - base >= 64) ? 64 : (n - base);
        const ull wmask = (lim >= 64) ? ~0ull : ((1ull << lim) - 1ull);
        ull curw = rlane_u64(remv_l, W);
        ull heavy = rlane_u64(rany_l, W) & wmask;
        while (heavy) {
            const int j = __ffsll((long long)heavy) - 1;
            heavy &= heavy - 1;
            if (!((curw >> j) & 1ull)) {          // heavy row live -> apply its mask
                ull mrow = lmask[(base + j) * 17 + lane];
                remv_l |= mrow;
                curw |= rlane_u64(mrow, W);
            }
        }
        // keep-word: mask bits only point forward, so word W is final at window end
        kpv = (lane == W) ? (~curw & wmask) : kpv;
    }

    // ---- order-preserving compaction (r14 verbatim, LDS key reads)
    int myc = __popcll(kpv);
    int pos = 0, tot = 0;
    for (int w2 = 0; w2 < 16; ++w2) {
        int c = __builtin_amdgcn_readlane(myc, w2);
        pos += (w2 < lane) ? c : 0;
        tot += c;
    }
    if (lane == 0) kcount[g] = tot;
    ull kw = kpv;
    while (kw) {
        int bit = __ffsll((long long)kw) - 1;
        kw &= kw - 1;
        klist[g * ROWS + pos] = lsk[(lane << 6) + bit];
        ++pos;
    }
}

// -------------------------------------------------------- K8: rank-merge finalize
__global__ void __launch_bounds__(1024)
final_kernel(const float4* __restrict__ cand_box, const ull* __restrict__ klist,
             const int* __restrict__ kcount, float* __restrict__ out) {
    const int img = blockIdx.x >> 2, chunk = blockIdx.x & 3;
    const int tid = threadIdx.x;
    __shared__ ull keys[K_TOT];
    __shared__ int base[6];
    if (tid == 0) {
        int s = 0;
        for (int l = 0; l < 5; ++l) { base[l] = s; s += kcount[img * 5 + l]; }
        base[5] = s;
    }
    __syncthreads();
    const int total = base[5];
    for (int l = 0; l < 5; ++l) {
        int cnt = base[l + 1] - base[l];
        for (int j = tid; j < cnt; j += 1024)
            keys[base[l] + j] = klist[(img * 5 + l) * ROWS + j];
    }
    __syncthreads();

    float* boxes_out = out;                       // [16][1000][4]
    float* scores_out = out + B_IMG * 1000 * 4;   // [16][1000]

    for (int i = chunk * 1024 + tid; i < total; i += 4096) {
        int L = 0;
        while (i >= base[L + 1]) ++L;
        ull x = keys[i];
        int grank = i - base[L];
        #pragma unroll
        for (int M = 0; M < 5; ++M) {
            if (M == L) continue;
            int lo = base[M], hi = base[M + 1];
            while (lo < hi) {
                int mid = (lo + hi) >> 1;
                if (keys[mid] > x) lo = mid + 1; else hi = mid;
            }
            grank += lo - base[M];
        }
        if (grank < 1000) {
            int slot = (int)(~(unsigned)x);
            float4 bb = cand_box[img * K_TOT + slot];
            ((float4*)boxes_out)[img * 1000 + grank] = bb;
            scores_out[img * 1000 + grank] = inv_fkey((unsigned)(x >> 32));
        }
    }
    if (chunk == 0) {
        for (int r = total + tid; r < 1000; r += 1024) {
            ((float4*)boxes_out)[img * 1000 + r] = make_float4(0.f, 0.f, 0.f, 0.f);
            scores_out[img * 1000 + r] = 0.f;
        }
    }
}

// ---------------------------------------------------------------- launch
extern "C" void kernel_launch(void* const* d_in, const int* in_sizes, int n_in,
                              void* d_out, int out_size, void* d_ws, size_t ws_size,
                              hipStream_t stream) {
    const float* obj = (const float*)d_in[0];
    const float* deltas = (const float*)d_in[1];
    const float* anchors = (const float*)d_in[2];
    const int* ih = (const int*)d_in[3];
    const int* iw = (const int*)d_in[4];
    float* out = (float*)d_out;

    char* p = (char*)d_ws;
    float4* cand_box = (float4*)p;   p += (size_t)B_IMG * K_TOT * sizeof(float4);   // 1.22 MB
    float4* sbox = (float4*)p;       p += (size_t)80 * ROWS * sizeof(float4);       // 1.31 MB
    // union region: maskg (used by K6/K7) overlays gkeys+phist+sghist (dead after K4)
    char* upool = p;                 p += (size_t)80 * 16 * ROWS * sizeof(ull);     // 10.49 MB
    ull* maskg = (ull*)upool;
    ull* gkeys = (ull*)upool;                                                       // 2.62 MB
    unsigned* phist = (unsigned*)(upool + (size_t)80 * CAPG * sizeof(ull));         // 4.72 MB
    unsigned* sghist = (unsigned*)(upool + (size_t)80 * CAPG * sizeof(ull)
                                   + (size_t)288 * 4096 * sizeof(unsigned));        // 1.31 MB
    ull* svalid = (ull*)p;           p += (size_t)80 * 16 * sizeof(ull);
    ull* growany = (ull*)p;          p += (size_t)80 * 16 * sizeof(ull);
    ull* skeys = (ull*)p;            p += (size_t)80 * ROWS * sizeof(ull);          // 640 KB
    ull* klist = (ull*)p;            p += (size_t)80 * ROWS * sizeof(ull);          // 640 KB
    float* cand_masked = (float*)p;  p += (size_t)B_IMG * K_TOT * sizeof(float);
    float* sar = (float*)p;          p += (size_t)80 * ROWS * sizeof(float);
    int* kcount = (int*)p;           p += 512;
    float* mclvl = (float*)p;        p += 512;
    unsigned* Tg = (unsigned*)p;     p += 512;
    int* flagg = (int*)p;            p += 512;
    int* gcnt = (int*)p;             p += 512;

    hipLaunchKernelGGL(hist_kernel, dim3(B_IMG * SL_PER_IMG), dim3(256), 0, stream,
                       obj, phist);
    hipLaunchKernelGGL(thresh_kernel, dim3(80), dim3(1024), 0, stream,
                       phist, sghist, Tg, flagg, gcnt);
    hipLaunchKernelGGL(collect_kernel, dim3(B_IMG * SL_PER_IMG), dim3(256), 0, stream,
                       obj, Tg, flagg, gkeys, gcnt);
    hipLaunchKernelGGL(sortgather_kernel, dim3(80), dim3(1024), 0, stream,
                       obj, deltas, anchors, ih, iw, sghist, Tg, flagg, gkeys, gcnt,
                       cand_box, cand_masked, mclvl);
    hipLaunchKernelGGL(sortprep_kernel, dim3(80), dim3(1024), 0, stream,
                       cand_box, cand_masked, mclvl, sbox, sar, skeys, svalid, growany);
    hipLaunchKernelGGL(maskbuild_kernel, dim3(TOTAL_JOBS / 4), dim3(256), 0, stream,
                       sbox, sar, maskg, growany);
    hipLaunchKernelGGL(scan_kernel, dim3(80), dim3(1024), 0, stream,
                       maskg, growany, svalid, skeys, klist, kcount);
    hipLaunchKernelGGL(final_kernel, dim3(64), dim3(1024), 0, stream,
                       cand_box, klist, kcount, out);
}

// Round 23
// 134.514 us; speedup vs baseline: 1.1818x; 1.1818x over previous
//
#include <hip/hip_runtime.h>

// RegionProposalNetwork post-processing for MI355X — full-device pipeline.
//  K1 hist     : 288 balanced slices -> PRIVATE per-slice 12-bit histograms
//  K2 thresh   : per (image,level) sum slice histograms -> threshold bin T (+ flag);
//                writes summed hist (exact fallback) and zeroes gcnt
//  K3 collect  : 288 slices -> compact u >= T into per-level global key lists
//  K4 sortgather: per (image,level) bitonic sort of collected keys (== lax.top_k
//                order) + fused gather/decode/clip/sigmoid/validity + per-level max
//                (fallback: exact radix refine for pathological ties)
//  K5 sortprep : STABLE PARTITION (== the bitonic; proof in r21)
//  K6 maskbuild: one 64x64 IoU tile per wave; LDS column staging; diag/offdiag split;
//                division-free IoU decision (exact division fallback in-band)
//  K7 scan     : heavy-rows-only staging (rowany-gated) + r9-verified windowed walk
//  K8 final    : rank-merge of 5 sorted kept lists per image
// NOTE: gkeys/phist/sghist are overlaid on maskg (all consumed before maskbuild writes).

#define A_TOTAL 261888
#define B_IMG   16
#define K_TOT   4768
#define NEGV    -1e9f
#define BBOX_CLIP 4.135166556742356f  // log(1000/16)
#define ROWS    1024
#define JOBS_PER_IMG 622              // 4*136 + 78
#define TOTAL_JOBS   9952             // 16*622
#define CAPG    4096
#define SL_PER_IMG 18

__constant__ int c_lvl_off[5] = {0, 196608, 245760, 258048, 261120};
__constant__ int c_lvl_n[5]   = {196608, 49152, 12288, 3072, 768};
__constant__ int c_lvl_k[5]   = {1000, 1000, 1000, 1000, 768};
__constant__ int c_sel_off[5] = {0, 1000, 2000, 3000, 4000};
__constant__ int c_lvl_sst[5] = {0, 12, 15, 16, 17};   // slice start within image
__constant__ int c_lvl_scn[5] = {12, 3, 1, 1, 1};      // slice count

__constant__ int c_s_lvl[SL_PER_IMG]   = {0,0,0,0,0,0,0,0,0,0,0,0, 1,1,1, 2, 3, 4};
__constant__ int c_s_base4[SL_PER_IMG] = {0,4096,8192,12288,16384,20480,24576,28672,
                                          32768,36864,40960,45056, 0,4096,8192, 0, 0, 0};
__constant__ int c_s_len4[SL_PER_IMG]  = {4096,4096,4096,4096,4096,4096,4096,4096,
                                          4096,4096,4096,4096, 4096,4096,4096, 3072, 768, 192};

typedef unsigned long long ull;

__device__ __forceinline__ unsigned fkey(float f) {
    unsigned u = __float_as_uint(f);
    return (u & 0x80000000u) ? ~u : (u | 0x80000000u);
}
__device__ __forceinline__ float inv_fkey(unsigned h) {
    return (h & 0x80000000u) ? __uint_as_float(h ^ 0x80000000u)
                             : __uint_as_float(~h);
}
__device__ __forceinline__ ull rlane_u64(ull v, int l) {
    int lo = __builtin_amdgcn_readlane((int)(unsigned)v, l);
    int hi = __builtin_amdgcn_readlane((int)(unsigned)(v >> 32), l);
    return ((ull)(unsigned)hi << 32) | (unsigned)lo;
}

// IoU decision: fdiv_rn(inter,den) > 0.7f, resolved without division outside a
// conservative band (rel 1e-6 >> all rounding effects); in-band lanes use the
// EXACT original division -> decision bit identical for every pair.
__device__ __forceinline__ bool iou_gt(float inter, float den) {
    float thr  = __fmul_rn(0.7f, den);
    float band = __fmul_rn(thr, 1.0e-6f);
    if (inter > __fadd_rn(thr, band)) return true;
    if (inter < __fsub_rn(thr, band)) return false;
    return (inter / den) > 0.7f;
}

// r17-proven bitonic sort (barrier every stage; compiler-friendly b64 LDS ops)
__device__ __forceinline__ void bitonic_desc(ull* keys, int S, int tid, int nth) {
    for (int kk = 2; kk <= S; kk <<= 1) {
        for (int jj = kk >> 1; jj > 0; jj >>= 1) {
            for (int i = tid; i < S; i += nth) {
                int ix = i ^ jj;
                if (ix > i) {
                    ull a = keys[i], c = keys[ix];
                    bool desc = ((i & kk) == 0);
                    if (desc ? (a < c) : (a > c)) { keys[i] = c; keys[ix] = a; }
                }
            }
            __syncthreads();
        }
    }
}

// ------------------------------------------- K1: private per-slice histogram
__global__ void __launch_bounds__(256)
hist_kernel(const float* __restrict__ obj, unsigned* __restrict__ phist) {
    const int blk = blockIdx.x, b = blk / SL_PER_IMG, r = blk % SL_PER_IMG;
    const int lvl = c_s_lvl[r], base4 = c_s_base4[r], len4 = c_s_len4[r];
    const int tid = threadIdx.x;
    const float4* src4 = (const float4*)(obj + (size_t)b * A_TOTAL + c_lvl_off[lvl]) + base4;

    __shared__ unsigned lh[2 * 4096];
    for (int i = tid; i < 2 * 4096; i += 256) lh[i] = 0u;
    __syncthreads();
    unsigned* myh = lh + (tid & 1) * 4096;
    for (int i = tid; i < len4; i += 256) {
        float4 v = src4[i];
        atomicAdd(&myh[fkey(v.x) >> 20], 1u);
        atomicAdd(&myh[fkey(v.y) >> 20], 1u);
        atomicAdd(&myh[fkey(v.z) >> 20], 1u);
        atomicAdd(&myh[fkey(v.w) >> 20], 1u);
    }
    __syncthreads();
    for (int bin = tid; bin < 4096; bin += 256)
        phist[(size_t)blk * 4096 + bin] = lh[bin] + lh[4096 + bin];
}

// --------------------- K2: sum slices -> threshold (+ summed hist, gcnt zero)
__global__ void __launch_bounds__(1024)
thresh_kernel(const unsigned* __restrict__ phist, unsigned* __restrict__ sghist,
              unsigned* __restrict__ Tg, int* __restrict__ flagg,
              int* __restrict__ gcnt) {
    const int g = blockIdx.x, b = g / 5, lvl = g % 5;
    const int n = c_lvl_n[lvl], k = c_lvl_k[lvl];
    const int tid = threadIdx.x;
    if (tid == 0) gcnt[g] = 0;
    if (k >= n) {
        if (tid == 0) { Tg[g] = 0u; flagg[g] = 0; }
        return;
    }
    const int sst = b * SL_PER_IMG + c_lvl_sst[lvl], scn = c_lvl_scn[lvl];
    __shared__ unsigned csum[1024];
    __shared__ int sh_chunk;
    __shared__ unsigned hist4[4096];
    unsigned s = 0;
    for (int q = 0; q < 4; ++q) {
        const int bin = tid * 4 + q;
        unsigned v = 0;
        for (int s2 = 0; s2 < scn; ++s2)
            v += phist[(size_t)(sst + s2) * 4096 + bin];
        hist4[bin] = v;
        sghist[g * 4096 + bin] = v;     // exact summed hist for the fallback path
        s += v;
    }
    csum[tid] = s;
    __syncthreads();
    for (int o = 1; o < 1024; o <<= 1) {
        unsigned v = (tid + o < 1024) ? csum[tid + o] : 0u;
        __syncthreads();
        csum[tid] += v;
        __syncthreads();
    }
    if (csum[tid] >= (unsigned)k && (tid == 1023 || csum[tid + 1] < (unsigned)k))
        sh_chunk = tid;
    __syncthreads();
    if (tid == 0) {
        int I = sh_chunk;
        unsigned cum = (I < 1023) ? csum[I + 1] : 0u;
        unsigned bin = 0, cntge = 0;
        for (int c = I * 4 + 3; c >= I * 4; --c) {
            unsigned h = hist4[c];
            if (cum + h >= (unsigned)k) { bin = (unsigned)c; cntge = cum + h; break; }
            cum += h;
        }
        if (cntge <= CAPG) { Tg[g] = bin << 20; flagg[g] = 0; }
        else               { Tg[g] = 0u;        flagg[g] = 1; }
    }
}

// ------------------------------------------------------------ K3: collect
__global__ void __launch_bounds__(256)
collect_kernel(const float* __restrict__ obj, const unsigned* __restrict__ Tg,
               const int* __restrict__ flagg, ull* __restrict__ gkeys,
               int* __restrict__ gcnt) {
    const int blk = blockIdx.x, b = blk / SL_PER_IMG, r = blk % SL_PER_IMG;
    const int lvl = c_s_lvl[r], base4 = c_s_base4[r], len4 = c_s_len4[r];
    const int g = b * 5 + lvl;
    const int tid = threadIdx.x;
    if (flagg[g]) return;
    const unsigned T = Tg[g];
    const float4* src4 = (const float4*)(obj + (size_t)b * A_TOTAL + c_lvl_off[lvl]) + base4;

    __shared__ ull buf[CAPG];
    __shared__ int scnt, sbase;
    if (tid == 0) scnt = 0;
    __syncthreads();
    for (int i = tid; i < len4; i += 256) {
        float4 v = src4[i];
        unsigned u0 = fkey(v.x), u1 = fkey(v.y), u2 = fkey(v.z), u3 = fkey(v.w);
        int al = (base4 + i) << 2;
        if (u0 >= T) { int p = atomicAdd(&scnt, 1); if (p < CAPG) buf[p] = ((ull)u0 << 32) | (unsigned)(~(unsigned)(al + 0)); }
        if (u1 >= T) { int p = atomicAdd(&scnt, 1); if (p < CAPG) buf[p] = ((ull)u1 << 32) | (unsigned)(~(unsigned)(al + 1)); }
        if (u2 >= T) { int p = atomicAdd(&scnt, 1); if (p < CAPG) buf[p] = ((ull)u2 << 32) | (unsigned)(~(unsigned)(al + 2)); }
        if (u3 >= T) { int p = atomicAdd(&scnt, 1); if (p < CAPG) buf[p] = ((ull)u3 << 32) | (unsigned)(~(unsigned)(al + 3)); }
    }
    __syncthreads();
    int c2 = scnt < CAPG ? scnt : CAPG;
    if (tid == 0) sbase = atomicAdd(&gcnt[g], c2);
    __syncthreads();
    for (int j = tid; j < c2; j += 256) {
        int d = sbase + j;
        if (d < CAPG) gkeys[g * CAPG + d] = buf[j];
    }
}

// ---------------------------------------- K4: sort collected + fused gather
__global__ void __launch_bounds__(1024)
sortgather_kernel(const float* __restrict__ obj, const float* __restrict__ deltas,
                  const float* __restrict__ anchors, const int* __restrict__ ihp,
                  const int* __restrict__ iwp, const unsigned* __restrict__ sghist,
                  const unsigned* __restrict__ Tg, const int* __restrict__ flagg,
                  const ull* __restrict__ gkeys, const int* __restrict__ gcnt,
                  float4* __restrict__ cand_box, float* __restrict__ cand_masked,
                  float* __restrict__ mclvl) {
    const int g = blockIdx.x, b = g / 5, lvl = g % 5;
    const int n = c_lvl_n[lvl], k = c_lvl_k[lvl], off = c_lvl_off[lvl];
    const int so = c_sel_off[lvl];
    const int tid = threadIdx.x;

    __shared__ ull cl[CAPG];
    __shared__ float redf[1024];
    __shared__ unsigned fhist[256];
    __shared__ unsigned csum[1024];
    __shared__ int sh_chunk, sh_rem, sh_cnt;
    __shared__ unsigned sh_bin;

    int cnt;
    if (!flagg[g]) {
        cnt = gcnt[g];
        if (cnt < 0) cnt = 0;
        if (cnt > CAPG) cnt = CAPG;
        for (int i = tid; i < cnt; i += 1024) cl[i] = gkeys[g * CAPG + i];
    } else {
        // ---- pathological-tie fallback: single-block radix refine (reads src) ----
        const float4* src4 = (const float4*)(obj + (size_t)b * A_TOTAL + off);
        const int n4 = n >> 2;
        unsigned s = 0;
        for (int q = 0; q < 4; ++q) s += sghist[g * 4096 + tid * 4 + q];
        csum[tid] = s;
        __syncthreads();
        for (int o = 1; o < 1024; o <<= 1) {
            unsigned v = (tid + o < 1024) ? csum[tid + o] : 0u;
            __syncthreads();
            csum[tid] += v;
            __syncthreads();
        }
        if (csum[tid] >= (unsigned)k && (tid == 1023 || csum[tid + 1] < (unsigned)k))
            sh_chunk = tid;
        __syncthreads();
        if (tid == 0) {
            int I = sh_chunk;
            unsigned cum = (I < 1023) ? csum[I + 1] : 0u;
            for (int c = I * 4 + 3; c >= I * 4; --c) {
                unsigned h = sghist[g * 4096 + c];
                if (cum + h >= (unsigned)k) { sh_bin = (unsigned)c; sh_rem = k - (int)cum; break; }
                cum += h;
            }
        }
        __syncthreads();
        unsigned prefix = sh_bin;
        int rem = sh_rem, done = 12;
        while (done < 32) {
            int w = (32 - done >= 8) ? 8 : (32 - done);
            int shift = 32 - done - w;
            int nb = 1 << w;
            for (int i = tid; i < nb; i += 1024) fhist[i] = 0u;
            __syncthreads();
            for (int i = tid; i < n4; i += 1024) {
                float4 v = src4[i];
                unsigned uu0 = fkey(v.x), uu1 = fkey(v.y), uu2 = fkey(v.z), uu3 = fkey(v.w);
                if ((uu0 >> (shift + w)) == prefix) atomicAdd(&fhist[(uu0 >> shift) & (nb - 1)], 1u);
                if ((uu1 >> (shift + w)) == prefix) atomicAdd(&fhist[(uu1 >> shift) & (nb - 1)], 1u);
                if ((uu2 >> (shift + w)) == prefix) atomicAdd(&fhist[(uu2 >> shift) & (nb - 1)], 1u);
                if ((uu3 >> (shift + w)) == prefix) atomicAdd(&fhist[(uu3 >> shift) & (nb - 1)], 1u);
            }
            __syncthreads();
            if (tid == 0) {
                unsigned cum = 0;
                for (int c = nb - 1; c >= 0; --c) {
                    unsigned h = fhist[c];
                    if (cum + h >= (unsigned)rem) {
                        sh_bin = (prefix << w) | (unsigned)c;
                        sh_rem = rem - (int)cum;
                        break;
                    }
                    cum += h;
                }
            }
            __syncthreads();
            prefix = sh_bin; rem = sh_rem; done += w;
            __syncthreads();
        }
        unsigned T = prefix;
        if (tid == 0) sh_cnt = 0;
        __syncthreads();
        for (int i = tid; i < n4; i += 1024) {
            float4 v = src4[i];
            unsigned u0 = fkey(v.x), u1 = fkey(v.y), u2 = fkey(v.z), u3 = fkey(v.w);
            int base = i << 2;
            if (u0 >= T) { int p = atomicAdd(&sh_cnt, 1); if (p < CAPG) cl[p] = ((ull)u0 << 32) | (unsigned)(~(unsigned)(base + 0)); }
            if (u1 >= T) { int p = atomicAdd(&sh_cnt, 1); if (p < CAPG) cl[p] = ((ull)u1 << 32) | (unsigned)(~(unsigned)(base + 1)); }
            if (u2 >= T) { int p = atomicAdd(&sh_cnt, 1); if (p < CAPG) cl[p] = ((ull)u2 << 32) | (unsigned)(~(unsigned)(base + 2)); }
            if (u3 >= T) { int p = atomicAdd(&sh_cnt, 1); if (p < CAPG) cl[p] = ((ull)u3 << 32) | (unsigned)(~(unsigned)(base + 3)); }
        }
        __syncthreads();
        cnt = sh_cnt; if (cnt > CAPG) cnt = CAPG;
    }

    int S = 1024; while (S < cnt) S <<= 1;
    for (int i = cnt + tid; i < S; i += 1024) cl[i] = 0ull;
    __syncthreads();
    bitonic_desc(cl, S, tid, 1024);

    // ---- fused gather/decode (rank tid, key in cl[tid]) ----
    const float imh = (float)ihp[0];
    const float imw = (float)iwp[0];
    float mx = 0.0f;
    if (tid < k) {
        ull kv = cl[tid];
        unsigned idx = (unsigned)off + (unsigned)(~(unsigned)kv);
        float logit = inv_fkey((unsigned)(kv >> 32));
        float4 anc = ((const float4*)anchors)[idx];
        float w = __fsub_rn(anc.z, anc.x);
        float h = __fsub_rn(anc.w, anc.y);
        float cx = __fadd_rn(anc.x, __fmul_rn(0.5f, w));
        float cy = __fadd_rn(anc.y, __fmul_rn(0.5f, h));
        float4 dl = ((const float4*)deltas)[(size_t)b * A_TOTAL + idx];
        float dx = dl.x, dy = dl.y;
        float dw = fminf(dl.z, BBOX_CLIP);
        float dh = fminf(dl.w, BBOX_CLIP);
        float pcx = __fadd_rn(__fmul_rn(dx, w), cx);
        float pcy = __fadd_rn(__fmul_rn(dy, h), cy);
        float pw = __fmul_rn(expf(dw), w);
        float ph = __fmul_rn(expf(dh), h);
        float x1 = __fsub_rn(pcx, __fmul_rn(0.5f, pw));
        float y1 = __fsub_rn(pcy, __fmul_rn(0.5f, ph));
        float x2 = __fadd_rn(pcx, __fmul_rn(0.5f, pw));
        float y2 = __fadd_rn(pcy, __fmul_rn(0.5f, ph));
        x1 = fminf(fmaxf(x1, 0.0f), imw);
        y1 = fminf(fmaxf(y1, 0.0f), imh);
        x2 = fminf(fmaxf(x2, 0.0f), imw);
        y2 = fminf(fmaxf(y2, 0.0f), imh);
        float score = 1.0f / __fadd_rn(1.0f, expf(-logit));
        bool valid = (__fsub_rn(x2, x1) >= 0.001f) && (__fsub_rn(y2, y1) >= 0.001f);
        cand_box[b * K_TOT + so + tid] = make_float4(x1, y1, x2, y2);
        cand_masked[b * K_TOT + so + tid] = valid ? score : NEGV;
        mx = fmaxf(fmaxf(x1, y1), fmaxf(x2, y2));
    }
    redf[tid] = mx;
    __syncthreads();
    for (int s2 = 512; s2 > 0; s2 >>= 1) {
        if (tid < s2) redf[tid] = fmaxf(redf[tid], redf[tid + s2]);
        __syncthreads();
    }
    if (tid == 0) mclvl[g] = redf[0];
}

// ------ K5: stable valid/invalid partition (== r7 bitonic; proof in r21)
__global__ void __launch_bounds__(1024)
sortprep_kernel(const float4* __restrict__ cand_box, const float* __restrict__ cand_masked,
                const float* __restrict__ mclvl,
                float4* __restrict__ sbox, float* __restrict__ sar,
                ull* __restrict__ skeys, ull* __restrict__ svalid,
                ull* __restrict__ growany) {
    const int g = blockIdx.x, b = g / 5, lvl = g % 5;
    const int n = c_lvl_k[lvl], so = c_sel_off[lvl];
    const int tid = threadIdx.x;
    const int wid = tid >> 6, lane = tid & 63;
    __shared__ int wsum[16];
    __shared__ int wbase[17];

    const bool inrange = tid < n;
    float m = 0.0f;
    bool valid = false;
    if (inrange) {
        m = cand_masked[b * K_TOT + so + tid];
        valid = (m > -1e8f);
    }
    ull bal  = __ballot(valid);                  // valid => inrange
    ull ibal = __ballot(inrange && !valid);
    ull ltmask = lane ? (~0ull >> (64 - lane)) : 0ull;
    int lpre  = __popcll(bal & ltmask);
    int lprei = __popcll(ibal & ltmask);
    if (lane == 0) wsum[wid] = __popcll(bal);
    __syncthreads();
    if (tid == 0) {
        int s = 0;
        for (int w = 0; w < 16; ++w) { wbase[w] = s; s += wsum[w]; }
        wbase[16] = s;
    }
    __syncthreads();
    const int nv = wbase[16];

    float mc = fmaxf(fmaxf(fmaxf(mclvl[b * 5 + 0], mclvl[b * 5 + 1]),
                           fmaxf(mclvl[b * 5 + 2], mclvl[b * 5 + 3])),
                     mclvl[b * 5 + 4]);
    const float offs = __fmul_rn((float)lvl, __fadd_rn(mc, 1.0f));

    if (inrange) {
        int r;
        if (valid) r = wbase[wid] + lpre;
        else       r = nv + (wid * 64 - wbase[wid]) + lprei;
        skeys[g * ROWS + r] = ((ull)fkey(m) << 32) | (unsigned)(~(unsigned)(so + tid));
        float4 bb = cand_box[b * K_TOT + so + tid];
        float X1 = __fadd_rn(bb.x, offs);
        float Y1 = __fadd_rn(bb.y, offs);
        float X2 = __fadd_rn(bb.z, offs);
        float Y2 = __fadd_rn(bb.w, offs);
        sbox[g * ROWS + r] = make_float4(X1, Y1, X2, Y2);
        sar[g * ROWS + r] = __fmul_rn(fmaxf(__fsub_rn(X2, X1), 0.0f),
                                      fmaxf(__fsub_rn(Y2, Y1), 0.0f));
    } else {
        skeys[g * ROWS + tid] = 0ull;
        sbox[g * ROWS + tid] = make_float4(0.f, 0.f, 0.f, 0.f);
        sar[g * ROWS + tid] = 0.f;
    }
    if (tid < 16) {
        int lo = nv - tid * 64; lo = lo < 0 ? 0 : (lo > 64 ? 64 : lo);
        int hi = n - tid * 64;  hi = hi < 0 ? 0 : (hi > 64 ? 64 : hi);
        ull wlo = (lo >= 64) ? ~0ull : ((1ull << lo) - 1ull);
        ull whi = (hi >= 64) ? ~0ull : ((1ull << hi) - 1ull);
        svalid[g * 16 + tid] = whi & ~wlo;
        growany[g * 16 + tid] = 0ull;
    }
}

// -------- K6: mask build (1 tile/wave), LDS column staging, diag split,
//          division-free IoU decision (exact fallback in-band)
__global__ void __launch_bounds__(256)
maskbuild_kernel(const float4* __restrict__ sbox, const float* __restrict__ sar,
                 ull* __restrict__ maskg, ull* __restrict__ growany) {
    const int wave = (blockIdx.x * 256 + threadIdx.x) >> 6;
    const int lane = threadIdx.x & 63;
    const int wv = threadIdx.x >> 6;
    __shared__ float4 scb[256];
    __shared__ float sca2[256];
    const int img = wave / JOBS_PER_IMG;
    int rem = wave - img * JOBS_PER_IMG;
    int lvl, t;
    if (rem >= 544) { lvl = 4; t = rem - 544; }
    else            { lvl = rem / 136; t = rem - lvl * 136; }
    const int g = img * 5 + lvl;
    const int Rp = (c_lvl_k[lvl] + 63) >> 6;  // 16 or 12
    int rt = 0, tt = t;
    while (tt >= Rp - rt) { tt -= Rp - rt; ++rt; }
    const int ct = rt + tt;
    const int r0 = rt << 6, c0 = ct << 6;

    const float4 rb = sbox[g * ROWS + r0 + lane];
    const float  ra = sar[g * ROWS + r0 + lane];
    scb[threadIdx.x]  = sbox[g * ROWS + c0 + lane];
    sca2[threadIdx.x] = sar[g * ROWS + c0 + lane];
    __syncthreads();
    const int row = r0 + lane;

    ull m = 0ull;
    if (rt == ct) {
        for (int jj = 0; jj < 64; ++jj) {
            float4 cbj = scb[(wv << 6) | jj];
            float aj   = sca2[(wv << 6) | jj];
            float xx1 = fmaxf(rb.x, cbj.x);
            float yy1 = fmaxf(rb.y, cbj.y);
            float xx2 = fminf(rb.z, cbj.z);
            float yy2 = fminf(rb.w, cbj.w);
            float inter = __fmul_rn(fmaxf(__fsub_rn(xx2, xx1), 0.0f),
                                    fmaxf(__fsub_rn(yy2, yy1), 0.0f));
            float den = __fadd_rn(__fsub_rn(__fadd_rn(ra, aj), inter), 1e-9f);
            bool s = iou_gt(inter, den) && (c0 + jj > row);
            m |= ((ull)s) << jj;
        }
    } else {
        // off-diagonal: c0 >= r0+64 > row, condition always true (bit-identical)
        for (int jj = 0; jj < 64; ++jj) {
            float4 cbj = scb[(wv << 6) | jj];
            float aj   = sca2[(wv << 6) | jj];
            float xx1 = fmaxf(rb.x, cbj.x);
            float yy1 = fmaxf(rb.y, cbj.y);
            float xx2 = fminf(rb.z, cbj.z);
            float yy2 = fminf(rb.w, cbj.w);
            float inter = __fmul_rn(fmaxf(__fsub_rn(xx2, xx1), 0.0f),
                                    fmaxf(__fsub_rn(yy2, yy1), 0.0f));
            float den = __fadd_rn(__fsub_rn(__fadd_rn(ra, aj), inter), 1e-9f);
            bool s = iou_gt(inter, den);
            m |= ((ull)s) << jj;
        }
    }
    maskg[(size_t)(g * 16 + ct) * ROWS + row] = m;
    // publish per-row "mask nonempty" (converged wave, one atomic per tile)
    ull ab = __ballot(m != 0ull);
    if (lane == 0 && ab)
        atomicOr(&growany[g * 16 + rt], ab);
}

// ----- K7: heavy-rows-only staging + r9-verified windowed greedy walk
__global__ void __launch_bounds__(1024)
scan_kernel(const ull* __restrict__ maskg, const ull* __restrict__ growany,
            const ull* __restrict__ svalid, const ull* __restrict__ skeys,
            ull* __restrict__ klist, int* __restrict__ kcount) {
    const int g = blockIdx.x, lvl = g % 5;
    const int n = c_lvl_k[lvl];          // 1000 or 768
    const int Rp = (n + 63) >> 6;        // 16 or 12
    const int tid = threadIdx.x;

    __shared__ ull lmask[1024 * 17];     // row-major, stride 17; only heavy rows staged
    __shared__ ull lsk[1024];            // sorted keys staged to LDS

    // ---- phase 1: stage ONLY heavy rows (rowany-gated) + all keys
    if (tid < n) {
        ull rw = growany[g * 16 + (tid >> 6)];
        if ((rw >> (tid & 63)) & 1ull) {
            #pragma unroll 16
            for (int w = 0; w < 16; ++w) {
                ull v = (w < Rp) ? maskg[(size_t)(g * 16 + w) * ROWS + tid] : 0ull;
                lmask[tid * 17 + w] = v;
            }
        }
        lsk[tid] = skeys[g * ROWS + tid];
    }
    __syncthreads();
    if (tid >= 16) return;

    // ---- phase 2: r9-VERIFIED windowed serial walk (16 lanes hold remv words)
    const int lane = tid;
    ull remv_l = svalid[g * 16 + lane];
    ull rany_l = growany[g * 16 + lane];
    ull kpv = 0ull;
    for (int W = 0; W < Rp; ++W) {
        const int base = W << 6;
        const int lim = (n - base >= 64) ? 64 : (n - base);
        const ull wmask = (lim >= 64) ? ~0ull : ((1ull << lim) - 1ull);
        ull curw = rlane_u64(remv_l, W);
        ull heavy = rlane_u64(rany_l, W) & wmask;
        while (heavy) {
            const int j = __ffsll((long long)heavy) - 1;
            heavy &= heavy - 1;
            if (!((curw >> j) & 1ull)) {          // heavy row live -> apply its mask
                ull mrow = lmask[(base + j) * 17 + lane];
                remv_l |= mrow;
                curw |= rlane_u64(mrow, W);
            }
        }
        // keep-word: mask bits only point forward, so word W is final at window end
        kpv = (lane == W) ? (~curw & wmask) : kpv;
    }

    // ---- order-preserving compaction (r14 verbatim, LDS key reads)
    int myc = __popcll(kpv);
    int pos = 0, tot = 0;
    for (int w2 = 0; w2 < 16; ++w2) {
        int c = __builtin_amdgcn_readlane(myc, w2);
        pos += (w2 < lane) ? c : 0;
        tot += c;
    }
    if (lane == 0) kcount[g] = tot;
    ull kw = kpv;
    while (kw) {
        int bit = __ffsll((long long)kw) - 1;
        kw &= kw - 1;
        klist[g * ROWS + pos] = lsk[(lane << 6) + bit];
        ++pos;
    }
}

// -------------------------------------------------------- K8: rank-merge finalize
__global__ void __launch_bounds__(1024)
final_kernel(const float4* __restrict__ cand_box, const ull* __restrict__ klist,
             const int* __restrict__ kcount, float* __restrict__ out) {
    const int img = blockIdx.x >> 2, chunk = blockIdx.x & 3;
    const int tid = threadIdx.x;
    __shared__ ull keys[K_TOT];
    __shared__ int base[6];
    if (tid == 0) {
        int s = 0;
        for (int l = 0; l < 5; ++l) { base[l] = s; s += kcount[img * 5 + l]; }
        base[5] = s;
    }
    __syncthreads();
    const int total = base[5];
    for (int l = 0; l < 5; ++l) {
        int cnt = base[l + 1] - base[l];
        for (int j = tid; j < cnt; j += 1024)
            keys[base[l] + j] = klist[(img * 5 + l) * ROWS + j];
    }
    __syncthreads();

    float* boxes_out = out;                       // [16][1000][4]
    float* scores_out = out + B_IMG * 1000 * 4;   // [16][1000]

    for (int i = chunk * 1024 + tid; i < total; i += 4096) {
        int L = 0;
        while (i >= base[L + 1]) ++L;
        ull x = keys[i];
        int grank = i - base[L];
        #pragma unroll
        for (int M = 0; M < 5; ++M) {
            if (M == L) continue;
            int lo = base[M], hi = base[M + 1];
            while (lo < hi) {
                int mid = (lo + hi) >> 1;
                if (keys[mid] > x) lo = mid + 1; else hi = mid;
            }
            grank += lo - base[M];
        }
        if (grank < 1000) {
            int slot = (int)(~(unsigned)x);
            float4 bb = cand_box[img * K_TOT + slot];
            ((float4*)boxes_out)[img * 1000 + grank] = bb;
            scores_out[img * 1000 + grank] = inv_fkey((unsigned)(x >> 32));
        }
    }
    if (chunk == 0) {
        for (int r = total + tid; r < 1000; r += 1024) {
            ((float4*)boxes_out)[img * 1000 + r] = make_float4(0.f, 0.f, 0.f, 0.f);
            scores_out[img * 1000 + r] = 0.f;
        }
    }
}

// ---------------------------------------------------------------- launch
extern "C" void kernel_launch(void* const* d_in, const int* in_sizes, int n_in,
                              void* d_out, int out_size, void* d_ws, size_t ws_size,
                              hipStream_t stream) {
    const float* obj = (const float*)d_in[0];
    const float* deltas = (const float*)d_in[1];
    const float* anchors = (const float*)d_in[2];
    const int* ih = (const int*)d_in[3];
    const int* iw = (const int*)d_in[4];
    float* out = (float*)d_out;

    char* p = (char*)d_ws;
    float4* cand_box = (float4*)p;   p += (size_t)B_IMG * K_TOT * sizeof(float4);   // 1.22 MB
    float4* sbox = (float4*)p;       p += (size_t)80 * ROWS * sizeof(float4);       // 1.31 MB
    // union region: maskg (used by K6/K7) overlays gkeys+phist+sghist (dead after K4)
    char* upool = p;                 p += (size_t)80 * 16 * ROWS * sizeof(ull);     // 10.49 MB
    ull* maskg = (ull*)upool;
    ull* gkeys = (ull*)upool;                                                       // 2.62 MB
    unsigned* phist = (unsigned*)(upool + (size_t)80 * CAPG * sizeof(ull));         // 4.72 MB
    unsigned* sghist = (unsigned*)(upool + (size_t)80 * CAPG * sizeof(ull)
                                   + (size_t)288 * 4096 * sizeof(unsigned));        // 1.31 MB
    ull* svalid = (ull*)p;           p += (size_t)80 * 16 * sizeof(ull);
    ull* growany = (ull*)p;          p += (size_t)80 * 16 * sizeof(ull);
    ull* skeys = (ull*)p;            p += (size_t)80 * ROWS * sizeof(ull);          // 640 KB
    ull* klist = (ull*)p;            p += (size_t)80 * ROWS * sizeof(ull);          // 640 KB
    float* cand_masked = (float*)p;  p += (size_t)B_IMG * K_TOT * sizeof(float);
    float* sar = (float*)p;          p += (size_t)80 * ROWS * sizeof(float);
    int* kcount = (int*)p;           p += 512;
    float* mclvl = (float*)p;        p += 512;
    unsigned* Tg = (unsigned*)p;     p += 512;
    int* flagg = (int*)p;            p += 512;
    int* gcnt = (int*)p;             p += 512;

    hipLaunchKernelGGL(hist_kernel, dim3(B_IMG * SL_PER_IMG), dim3(256), 0, stream,
                       obj, phist);
    hipLaunchKernelGGL(thresh_kernel, dim3(80), dim3(1024), 0, stream,
                       phist, sghist, Tg, flagg, gcnt);
    hipLaunchKernelGGL(collect_kernel, dim3(B_IMG * SL_PER_IMG), dim3(256), 0, stream,
                       obj, Tg, flagg, gkeys, gcnt);
    hipLaunchKernelGGL(sortgather_kernel, dim3(80), dim3(1024), 0, stream,
                       obj, deltas, anchors, ih, iw, sghist, Tg, flagg, gkeys, gcnt,
                       cand_box, cand_masked, mclvl);
    hipLaunchKernelGGL(sortprep_kernel, dim3(80), dim3(1024), 0, stream,
                       cand_box, cand_masked, mclvl, sbox, sar, skeys, svalid, growany);
    hipLaunchKernelGGL(maskbuild_kernel, dim3(TOTAL_JOBS / 4), dim3(256), 0, stream,
                       sbox, sar, maskg, growany);
    hipLaunchKernelGGL(scan_kernel, dim3(80), dim3(1024), 0, stream,
                       maskg, growany, svalid, skeys, klist, kcount);
    hipLaunchKernelGGL(final_kernel, dim3(64), dim3(1024), 0, stream,
                       cand_box, klist, kcount, out);
}